// Round 11
// baseline (12562.444 us; speedup 1.0000x reference)
//
#include <hip/hip_runtime.h>
#include <hip/hip_bf16.h>

// Problem constants (fixed shapes per reference setup_inputs; n_step = 200).
#define MM 64
#define NN 4096
#define KK 4096
#define NSTEP 200

typedef __bf16 bf16x8 __attribute__((ext_vector_type(8)));
typedef float  f32x4  __attribute__((ext_vector_type(4)));

static __device__ __forceinline__ unsigned short f2bf(float f) {
    __hip_bfloat16 h = __float2bfloat16(f);
    return __builtin_bit_cast(unsigned short, h);
}
static __device__ __forceinline__ float bf2f(unsigned short u) {
    __hip_bfloat16 h = __builtin_bit_cast(__hip_bfloat16, u);
    return __bfloat162float(h);
}

// Fragment layouts (mfma_f32_16x16x32_bf16, m89 mapping:
//   frag[lane=q*16+l16][j] = Mat[row16=l16][k=q*8+j]):
// A (g):  addr(m,kg) = ((kc*4 + (m>>4))*64 + q*16 + (m&15))*8 + j
// B (W):  addr(n,kg) = (((n>>4)*128 + kc)*64 + q*16 + (n&15))*8 + j

// ---------------------------------------------------------------------------
// Prologue 1: s = 0.5*(W[n][k]+W[k][n]), diag zero; (hi,lo) bf16 split,
// scattered into B-fragment order. 64x64 tiles, LDS transpose.
// ---------------------------------------------------------------------------
__global__ __launch_bounds__(256) void symm_kernel(const float* __restrict__ W,
                                                   unsigned short* __restrict__ Wfh,
                                                   unsigned short* __restrict__ Wfl) {
    __shared__ float T[64][65];
    const int tid = threadIdx.x;
    const int r0 = blockIdx.y * 64, c0 = blockIdx.x * 64;
#pragma unroll
    for (int i = 0; i < 4; ++i) {
        int lin = tid + i * 256;
        int cc  = lin >> 4;
        int r4  = (lin & 15) * 4;
        float4 v = *(const float4*)&W[(size_t)(c0 + cc) * NN + r0 + r4];
        T[cc][r4 + 0] = v.x; T[cc][r4 + 1] = v.y;
        T[cc][r4 + 2] = v.z; T[cc][r4 + 3] = v.w;
    }
    __syncthreads();
#pragma unroll
    for (int i = 0; i < 4; ++i) {
        int lin = tid + i * 256;
        int rr  = lin >> 4;
        int c4  = (lin & 15) * 4;
        float4 v = *(const float4*)&W[(size_t)(r0 + rr) * NN + c0 + c4];
        float d[4] = {v.x, v.y, v.z, v.w};
        ushort4 ohi, olo;
        unsigned short* ph = (unsigned short*)&ohi;
        unsigned short* pl = (unsigned short*)&olo;
#pragma unroll
        for (int j = 0; j < 4; ++j) {
            float sv = 0.5f * (d[j] + T[c4 + j][rr]);
            if (r0 + rr == c0 + c4 + j) sv = 0.0f;
            unsigned short hi = f2bf(sv);
            ph[j] = hi;
            pl[j] = f2bf(sv - bf2f(hi));
        }
        const int n  = r0 + rr;            // W row == output column
        const int kg = c0 + c4;            // 4-aligned
        const int s16 = n >> 4, ln = n & 15;
        const int kc = kg >> 5, q = (kg & 31) >> 3, j0 = kg & 7;
        size_t off = (((size_t)s16 * 128 + kc) * 64 + q * 16 + ln) * 8 + j0;
        *(ushort4*)&Wfh[off] = ohi;        // 8B-aligned
        *(ushort4*)&Wfl[off] = olo;
    }
}

// ---------------------------------------------------------------------------
// Prologue 2: x0 = (1/beta)*log(g/(1-g)) (plain layout); g -> A-frag (hi,lo)
// ---------------------------------------------------------------------------
__global__ __launch_bounds__(256) void init_kernel(const float* __restrict__ g_in,
                                                   const float* __restrict__ beta,
                                                   float* __restrict__ x,
                                                   unsigned short* __restrict__ gfh,
                                                   unsigned short* __restrict__ gfl) {
    int idx = blockIdx.x * 256 + threadIdx.x;
    int r = idx >> 12, c = idx & (NN - 1);
    float g = g_in[idx];
    x[idx] = logf(g / (1.0f - g)) / beta[c];
    unsigned short hi = f2bf(g);
    unsigned short lo = f2bf(g - bf2f(hi));
    size_t off = (((size_t)(c >> 5) * 4 + (r >> 4)) * 64 + ((c & 31) >> 3) * 16 + (r & 15)) * 8 + (c & 7);
    gfh[off] = hi;
    gfl[off] = lo;
}

// ---------------------------------------------------------------------------
// Prologue 3: max_x = 50 / max(beta)
// ---------------------------------------------------------------------------
__global__ __launch_bounds__(256) void maxx_kernel(const float* __restrict__ beta,
                                                   float* __restrict__ out) {
    __shared__ float red[256];
    float m = -1e30f;
    for (int i = threadIdx.x; i < NN; i += 256) m = fmaxf(m, beta[i]);
    red[threadIdx.x] = m;
    __syncthreads();
    for (int s = 128; s > 0; s >>= 1) {
        if (threadIdx.x < s) red[threadIdx.x] = fmaxf(red[threadIdx.x], red[threadIdx.x + s]);
        __syncthreads();
    }
    if (threadIdx.x == 0) out[0] = 50.0f / red[0];
}

// ---------------------------------------------------------------------------
// GEMM kernel v8: v7 + double-buffered LDS, 1 barrier/chunk, 2-deep prefetch.
// v7 (16.3 us/step) ran 16 chunks x 2 barriers with loads issued only ~6
// MFMAs before the vmcnt(0)-guarded LDS write -> exposed load latency every
// chunk (the classic 2-phase stall). v8: 64-k chunks (8/block), 2 x 32 KB
// LDS buffers, pipeline depth 2 (issue chunk it+2, write chunk it+1 -- one
// full iteration of latency cover, counted vmcnt -- compute chunk it),
// 9 barriers total (was 32), 12 MFMAs between stalls (was 6).
// Grid 512 = 64 strips x 8 K-eighths (2 blocks/CU, 128 KB LDS/CU); wave w:
// nq=w&3 (16-col group), mh=w>>2 (m-half), full K-eighth per wave -> acc
// final, direct P store. Summation order over kc identical to v7 (absmax
// canary 0.00390625). No cross-block sync (v3: fence+atomic=180 us/step).
// ---------------------------------------------------------------------------
__global__ __launch_bounds__(512, 4) void gemm_kernel(
    const unsigned short* __restrict__ gfh,
    const unsigned short* __restrict__ gfl,
    const unsigned short* __restrict__ Wfh,
    const unsigned short* __restrict__ Wfl,
    float* __restrict__ P)                    // [8][64][64][64] fp32 partials
{
    // Per buffer (16384 ushort = 32 KB), chunk = 2 kc:
    //  [0,2048) A-hi kc0 | [2048,4096) A-lo kc0 | [4096,8192) same kc1
    //  [8192,10240) B-hi kc0 {nq*512} | [10240,12288) B-lo kc0 | [12288,16384) kc1
    __shared__ unsigned short lds[2][16384];

    const int tid  = threadIdx.x;
    const int w    = tid >> 6;                // 0..7
    const int lane = tid & 63;
    const int s64  = blockIdx.x >> 3;         // 64-col strip 0..63
    const int kq8  = blockIdx.x & 7;          // K-eighth 0..7 (8 chunks of 64 k)
    const int nq   = w & 3;                   // wave's 16-col group in strip
    const int mh   = w >> 2;                  // wave's m-half (2 mq subtiles)

    // Staging map: thread t moves 64 B/chunk as 4 x 16 B pieces.
    const int tA  = (tid & 255) * 8;          // A elem within (kc)
    const int nq2 = (tid & 255) >> 6;
    const int eB  = (tid & 63) * 8;           // B elem within (nq2, kc)
    const unsigned short* __restrict__ srcA = (tid < 256) ? gfh : gfl;
    const unsigned short* __restrict__ srcB = (tid < 256) ? Wfh : Wfl;
    const size_t bRow = (size_t)(s64 * 4 + nq2) * 128;   // + kc, then *512

    f32x4 acc[2] = {};                        // 2 m-subtiles x (16x16) frag
    uint4 r1[4], r2[4];

    // Prologue: stage chunk 0 directly; issue chunk 1 into r1.
    {
        const int kc0 = kq8 * 16;
        uint4 a0 = *(const uint4*)&srcA[(size_t)kc0 * 2048 + tA];
        uint4 a1 = *(const uint4*)&srcA[(size_t)(kc0 + 1) * 2048 + tA];
        uint4 b0 = *(const uint4*)&srcB[(bRow + kc0) * 512 + eB];
        uint4 b1 = *(const uint4*)&srcB[(bRow + kc0 + 1) * 512 + eB];
        *(uint4*)&lds[0][tid * 8]         = a0;
        *(uint4*)&lds[0][4096 + tid * 8]  = a1;
        *(uint4*)&lds[0][8192 + tid * 8]  = b0;
        *(uint4*)&lds[0][12288 + tid * 8] = b1;
        const int kc1 = kq8 * 16 + 2;
        r1[0] = *(const uint4*)&srcA[(size_t)kc1 * 2048 + tA];
        r1[1] = *(const uint4*)&srcA[(size_t)(kc1 + 1) * 2048 + tA];
        r1[2] = *(const uint4*)&srcB[(bRow + kc1) * 512 + eB];
        r1[3] = *(const uint4*)&srcB[(bRow + kc1 + 1) * 512 + eB];
    }
    __syncthreads();

    int cur = 0;
    for (int it = 0; it < 8; ++it) {
        // Issue chunk it+2's loads (full iteration of latency cover).
        if (it < 6) {
            const int kcn = kq8 * 16 + (it + 2) * 2;
            r2[0] = *(const uint4*)&srcA[(size_t)kcn * 2048 + tA];
            r2[1] = *(const uint4*)&srcA[(size_t)(kcn + 1) * 2048 + tA];
            r2[2] = *(const uint4*)&srcB[(bRow + kcn) * 512 + eB];
            r2[3] = *(const uint4*)&srcB[(bRow + kcn + 1) * 512 + eB];
        }

        // Compute chunk it from lds[cur]: 2 kc x 6 MFMA.
        const unsigned short* L = &lds[cur][0];
#pragma unroll
        for (int j = 0; j < 2; ++j) {
            const int jo = j * 4096;
            bf16x8 bh = *(const bf16x8*)&L[8192 + jo + nq * 512 + lane * 8];
            bf16x8 bl = *(const bf16x8*)&L[10240 + jo + nq * 512 + lane * 8];
#pragma unroll
            for (int f = 0; f < 2; ++f) {
                const int mq = mh * 2 + f;
                bf16x8 ah = *(const bf16x8*)&L[jo + mq * 512 + lane * 8];
                bf16x8 al = *(const bf16x8*)&L[jo + 2048 + mq * 512 + lane * 8];
                acc[f] = __builtin_amdgcn_mfma_f32_16x16x32_bf16(ah, bh, acc[f], 0, 0, 0);
                acc[f] = __builtin_amdgcn_mfma_f32_16x16x32_bf16(al, bh, acc[f], 0, 0, 0);
                acc[f] = __builtin_amdgcn_mfma_f32_16x16x32_bf16(ah, bl, acc[f], 0, 0, 0);
            }
        }

        // Write chunk it+1 (r1, issued one iteration ago -> counted vmcnt).
        if (it < 7) {
            unsigned short* D = &lds[cur ^ 1][0];
            *(uint4*)&D[tid * 8]         = r1[0];
            *(uint4*)&D[4096 + tid * 8]  = r1[1];
            *(uint4*)&D[8192 + tid * 8]  = r1[2];
            *(uint4*)&D[12288 + tid * 8] = r1[3];
        }
        __syncthreads();
        if (it < 6) { r1[0] = r2[0]; r1[1] = r2[1]; r1[2] = r2[2]; r1[3] = r2[3]; }
        cur ^= 1;
    }

    // Direct P store: wave's acc is the complete K-eighth partial.
    // C-frag layout: value(row16=q*4+rg, col=l16) at lane q*16+l16, reg rg.
    {
        const int q = lane >> 4, l16 = lane & 15;
        float* Pb = &P[(size_t)(kq8 * 64 + s64) * 4096];
#pragma unroll
        for (int f = 0; f < 2; ++f) {
            const int mq = mh * 2 + f;
#pragma unroll
            for (int rg = 0; rg < 4; ++rg) {
                const int m = mq * 16 + q * 4 + rg;
                Pb[(size_t)m * 64 + nq * 16 + l16] = acc[f][rg];
            }
        }
    }
}

// ---------------------------------------------------------------------------
// Epilogue kernel: grid 256 x 256 thr; block b -> strip s64 = b>>2,
// row-quarter mq4 = b&3. Thread t: row, 4 cols. Sums 8 K-eighth partials,
// applies b/alpha/clip/sigmoid, updates x, writes next-step A-fragments.
// Cross-kernel P visibility via the dispatch boundary (baseline-proven).
// ---------------------------------------------------------------------------
__global__ __launch_bounds__(256) void epi_kernel(
    const float* __restrict__ P,
    float* __restrict__ x,
    unsigned short* __restrict__ gfh_out,
    unsigned short* __restrict__ gfl_out,
    const float* __restrict__ bvec,
    const float* __restrict__ beta,
    const float* __restrict__ tau,
    const float* __restrict__ dt_ptr,
    const float* __restrict__ maxx_ptr,
    float* __restrict__ gout_f32)             // non-null on last step only
{
    const int tid = threadIdx.x;
    const int s64 = blockIdx.x >> 2;
    const int mq4 = blockIdx.x & 3;
    const int m   = mq4 * 16 + (tid >> 4);    // batch row 0..63
    const int tt  = tid & 15;
    const int c0  = tt * 4;
    const int n0  = s64 * 64 + c0;            // global col, 4-aligned

    const size_t pb = ((size_t)s64 * 64 + m) * 64 + c0;
    float sum[4] = {};
#pragma unroll
    for (int k8 = 0; k8 < 8; ++k8) {
        float4 p = *(const float4*)&P[(size_t)k8 * 262144 + pb];
        sum[0] += p.x; sum[1] += p.y; sum[2] += p.z; sum[3] += p.w;
    }

    const float dt = *dt_ptr;
    const float mx = *maxx_ptr;
    float4 b0 = *(const float4*)&bvec[n0];
    float4 e0 = *(const float4*)&beta[n0];
    float4 t0 = *(const float4*)&tau[n0];
    float bb[4] = {b0.x, b0.y, b0.z, b0.w};
    float be[4] = {e0.x, e0.y, e0.z, e0.w};
    float tv[4] = {t0.x, t0.y, t0.z, t0.w};

    float* xp = &x[(size_t)m * NN + n0];
    float4 x0 = *(const float4*)xp;
    float xo[4] = {x0.x, x0.y, x0.z, x0.w};

    float gg[4];
    unsigned short vh[4], vl[4];
#pragma unroll
    for (int j = 0; j < 4; ++j) {
        const float al = dt / tv[j];
        float xn = al * (sum[j] + bb[j]) + (1.0f - al) * xo[j];
        xn = fminf(fmaxf(xn, -mx), mx);
        float g = 1.0f / (1.0f + __expf(-be[j] * xn));
        xo[j] = xn;
        gg[j] = g;
        unsigned short hi = f2bf(g);
        vh[j] = hi;
        vl[j] = f2bf(g - bf2f(hi));
    }
    *(float4*)xp = {xo[0], xo[1], xo[2], xo[3]};

    // A-fragment scatter for (m, kg = n0..n0+3); n0%8 in {0,4} -> ushort4.
    size_t off = (((size_t)(n0 >> 5) * 4 + (m >> 4)) * 64 + ((n0 & 31) >> 3) * 16 + (m & 15)) * 8 + (n0 & 7);
    *(ushort4*)&gfh_out[off] = {vh[0], vh[1], vh[2], vh[3]};
    *(ushort4*)&gfl_out[off] = {vl[0], vl[1], vl[2], vl[3]};

    if (gout_f32)
        *(float4*)&gout_f32[(size_t)m * NN + n0] = {gg[0], gg[1], gg[2], gg[3]};
}

// ---------------------------------------------------------------------------
extern "C" void kernel_launch(void* const* d_in, const int* in_sizes, int n_in,
                              void* d_out, int out_size, void* d_ws, size_t ws_size,
                              hipStream_t stream) {
    const float* state_g = (const float*)d_in[0];
    const float* W       = (const float*)d_in[1];
    const float* b       = (const float*)d_in[2];
    const float* beta    = (const float*)d_in[3];
    const float* tau     = (const float*)d_in[4];
    const float* dt      = (const float*)d_in[5];
    float* out = (float*)d_out;

    char* ws = (char*)d_ws;
    const size_t WH = (size_t)KK * NN * 2;    // 32 MB per W-frag array
    const size_t XB = (size_t)MM * NN * 4;    // 1 MB
    const size_t GB = (size_t)MM * NN * 2;    // 512 KB per g-frag array
    const size_t PB = (size_t)8 * 64 * 64 * 64 * 4;   // 8 MB partials
    unsigned short* Wfh = (unsigned short*)ws;
    unsigned short* Wfl = (unsigned short*)(ws + WH);
    float*          x   = (float*)(ws + 2 * WH);
    unsigned short* g0h = (unsigned short*)(ws + 2 * WH + XB);
    unsigned short* g0l = (unsigned short*)(ws + 2 * WH + XB + GB);
    unsigned short* g1h = (unsigned short*)(ws + 2 * WH + XB + 2 * GB);
    unsigned short* g1l = (unsigned short*)(ws + 2 * WH + XB + 3 * GB);
    float*          P   = (float*)(ws + 2 * WH + XB + 4 * GB);
    float*          mxp = (float*)(ws + 2 * WH + XB + 4 * GB + PB);

    symm_kernel<<<dim3(64, 64), 256, 0, stream>>>(W, Wfh, Wfl);
    init_kernel<<<(MM * NN) / 256, 256, 0, stream>>>(state_g, beta, x, g0h, g0l);
    maxx_kernel<<<1, 256, 0, stream>>>(beta, mxp);

    unsigned short *gih = g0h, *gil = g0l, *goh = g1h, *gol = g1l;
    for (int st = 0; st < NSTEP; ++st) {
        float* of = (st == NSTEP - 1) ? out : nullptr;
        gemm_kernel<<<512, 512, 0, stream>>>(gih, gil, Wfh, Wfl, P);
        epi_kernel<<<256, 256, 0, stream>>>(P, x, goh, gol, b, beta, tau, dt, mxp, of);
        unsigned short* tp;
        tp = gih; gih = goh; goh = tp;
        tp = gil; gil = gol; gol = tp;
    }
}

// Round 12
// 3528.409 us; speedup vs baseline: 3.5604x; 3.5604x over previous
//
#include <hip/hip_runtime.h>
#include <hip/hip_bf16.h>

// Problem constants (fixed shapes per reference setup_inputs; n_step = 200).
#define MM 64
#define NN 4096
#define KK 4096
#define NSTEP 200

typedef __bf16 bf16x8 __attribute__((ext_vector_type(8)));
typedef float  f32x4  __attribute__((ext_vector_type(4)));

static __device__ __forceinline__ unsigned short f2bf(float f) {
    __hip_bfloat16 h = __float2bfloat16(f);
    return __builtin_bit_cast(unsigned short, h);
}
static __device__ __forceinline__ float bf2f(unsigned short u) {
    __hip_bfloat16 h = __builtin_bit_cast(__hip_bfloat16, u);
    return __bfloat162float(h);
}

// Fragment layouts (mfma_f32_16x16x32_bf16, m89 mapping:
//   frag[lane=q*16+l16][j] = Mat[row16=l16][k=q*8+j]):
// A (g):  addr(m,kg) = ((kc*4 + (m>>4))*64 + q*16 + (m&15))*8 + j
// B (W):  addr(n,kg) = (((n>>4)*128 + kc)*64 + q*16 + (n&15))*8 + j

// ---------------------------------------------------------------------------
// Prologue 1: s = 0.5*(W[n][k]+W[k][n]), diag zero; (hi,lo) bf16 split,
// scattered into B-fragment order. 64x64 tiles, LDS transpose.
// ---------------------------------------------------------------------------
__global__ __launch_bounds__(256) void symm_kernel(const float* __restrict__ W,
                                                   unsigned short* __restrict__ Wfh,
                                                   unsigned short* __restrict__ Wfl) {
    __shared__ float T[64][65];
    const int tid = threadIdx.x;
    const int r0 = blockIdx.y * 64, c0 = blockIdx.x * 64;
#pragma unroll
    for (int i = 0; i < 4; ++i) {
        int lin = tid + i * 256;
        int cc  = lin >> 4;
        int r4  = (lin & 15) * 4;
        float4 v = *(const float4*)&W[(size_t)(c0 + cc) * NN + r0 + r4];
        T[cc][r4 + 0] = v.x; T[cc][r4 + 1] = v.y;
        T[cc][r4 + 2] = v.z; T[cc][r4 + 3] = v.w;
    }
    __syncthreads();
#pragma unroll
    for (int i = 0; i < 4; ++i) {
        int lin = tid + i * 256;
        int rr  = lin >> 4;
        int c4  = (lin & 15) * 4;
        float4 v = *(const float4*)&W[(size_t)(r0 + rr) * NN + c0 + c4];
        float d[4] = {v.x, v.y, v.z, v.w};
        ushort4 ohi, olo;
        unsigned short* ph = (unsigned short*)&ohi;
        unsigned short* pl = (unsigned short*)&olo;
#pragma unroll
        for (int j = 0; j < 4; ++j) {
            float sv = 0.5f * (d[j] + T[c4 + j][rr]);
            if (r0 + rr == c0 + c4 + j) sv = 0.0f;
            unsigned short hi = f2bf(sv);
            ph[j] = hi;
            pl[j] = f2bf(sv - bf2f(hi));
        }
        const int n  = r0 + rr;            // W row == output column
        const int kg = c0 + c4;            // 4-aligned
        const int s16 = n >> 4, ln = n & 15;
        const int kc = kg >> 5, q = (kg & 31) >> 3, j0 = kg & 7;
        size_t off = (((size_t)s16 * 128 + kc) * 64 + q * 16 + ln) * 8 + j0;
        *(ushort4*)&Wfh[off] = ohi;        // 8B-aligned
        *(ushort4*)&Wfl[off] = olo;
    }
}

// ---------------------------------------------------------------------------
// Prologue 2: x0 = (1/beta)*log(g/(1-g)) (plain layout); g -> A-frag (hi,lo)
// ---------------------------------------------------------------------------
__global__ __launch_bounds__(256) void init_kernel(const float* __restrict__ g_in,
                                                   const float* __restrict__ beta,
                                                   float* __restrict__ x,
                                                   unsigned short* __restrict__ gfh,
                                                   unsigned short* __restrict__ gfl) {
    int idx = blockIdx.x * 256 + threadIdx.x;
    int r = idx >> 12, c = idx & (NN - 1);
    float g = g_in[idx];
    x[idx] = logf(g / (1.0f - g)) / beta[c];
    unsigned short hi = f2bf(g);
    unsigned short lo = f2bf(g - bf2f(hi));
    size_t off = (((size_t)(c >> 5) * 4 + (r >> 4)) * 64 + ((c & 31) >> 3) * 16 + (r & 15)) * 8 + (c & 7);
    gfh[off] = hi;
    gfl[off] = lo;
}

// ---------------------------------------------------------------------------
// Prologue 3: max_x = 50 / max(beta)
// ---------------------------------------------------------------------------
__global__ __launch_bounds__(256) void maxx_kernel(const float* __restrict__ beta,
                                                   float* __restrict__ out) {
    __shared__ float red[256];
    float m = -1e30f;
    for (int i = threadIdx.x; i < NN; i += 256) m = fmaxf(m, beta[i]);
    red[threadIdx.x] = m;
    __syncthreads();
    for (int s = 128; s > 0; s >>= 1) {
        if (threadIdx.x < s) red[threadIdx.x] = fmaxf(red[threadIdx.x], red[threadIdx.x + s]);
        __syncthreads();
    }
    if (threadIdx.x == 0) out[0] = 50.0f / red[0];
}

// ---------------------------------------------------------------------------
// GEMM kernel v9 = v7 (best: 16.3 us/step) with chunk width doubled.
// v7: 16 chunks x 2 barriers = 32 barriers, 6 MFMAs of cover per exposure.
// v8's depth-2 double-buffer regressed 4x (unexplained; suspects: r1=r2
// register copy forcing vmcnt(0) drains / spill; no profile available) --
// that structure is excluded. v9 keeps v7's exact control flow (prefetch at
// iteration top into FRESH locals, compute, barrier, write, barrier) and
// only doubles the payload: chunk = 64k (2 kc), 8 chunks, 16 barriers,
// 12 MFMAs + 12 ds_reads between stalls, single 32 KB LDS buffer.
// Grid 512 = 64 strips x 8 K-eighths (2 blocks/CU); wave w: nq=w&3,
// mh=w>>2, full K-eighth per wave -> acc final, direct P store.
// Per-kc MFMA order identical to v7 -> absmax canary 0.00390625.
// ---------------------------------------------------------------------------
__global__ __launch_bounds__(512, 4) void gemm_kernel(
    const unsigned short* __restrict__ gfh,
    const unsigned short* __restrict__ gfl,
    const unsigned short* __restrict__ Wfh,
    const unsigned short* __restrict__ Wfl,
    float* __restrict__ P)                    // [8][64][64][64] fp32 partials
{
    // 32 KB, chunk = 2 kc:
    //  [0,2048) A-hi kc0 | [2048,4096) A-lo kc0 | [4096,8192) same for kc1
    //  [8192,10240) B-hi kc0 {nq*512} | [10240,12288) B-lo kc0 | [12288,16384) kc1
    __shared__ unsigned short lds[16384];

    const int tid  = threadIdx.x;
    const int w    = tid >> 6;                // 0..7
    const int lane = tid & 63;
    const int s64  = blockIdx.x >> 3;         // 64-col strip 0..63
    const int kq8  = blockIdx.x & 7;          // K-eighth 0..7 (8 chunks of 64 k)
    const int nq   = w & 3;                   // wave's 16-col group in strip
    const int mh   = w >> 2;                  // wave's m-half (2 mq subtiles)

    // Staging map: thread t moves 64 B/chunk as 4 x 16 B pieces.
    const int tA  = (tid & 255) * 8;          // A elem within (kc)
    const int nq2 = (tid & 255) >> 6;
    const int eB  = (tid & 63) * 8;           // B elem within (nq2, kc)
    const unsigned short* __restrict__ srcA = (tid < 256) ? gfh : gfl;
    const unsigned short* __restrict__ srcB = (tid < 256) ? Wfh : Wfl;
    const size_t bRow = (size_t)(s64 * 4 + nq2) * 128;   // + kc, then *512

    f32x4 acc[2] = {};                        // 2 m-subtiles x (16x16) frag

    // Prologue: stage chunk 0.
    {
        const int kc0 = kq8 * 16;
        uint4 a0 = *(const uint4*)&srcA[(size_t)kc0 * 2048 + tA];
        uint4 a1 = *(const uint4*)&srcA[(size_t)(kc0 + 1) * 2048 + tA];
        uint4 b0 = *(const uint4*)&srcB[(bRow + kc0) * 512 + eB];
        uint4 b1 = *(const uint4*)&srcB[(bRow + kc0 + 1) * 512 + eB];
        *(uint4*)&lds[tid * 8]         = a0;
        *(uint4*)&lds[4096 + tid * 8]  = a1;
        *(uint4*)&lds[8192 + tid * 8]  = b0;
        *(uint4*)&lds[12288 + tid * 8] = b1;
    }
    __syncthreads();

    for (int it = 0; it < 8; ++it) {
        // Issue next chunk's global loads early (fresh locals each iteration;
        // latency hides under the 12-MFMA compute phase).
        uint4 nA0, nA1, nB0, nB1;
        if (it < 7) {
            const int kcn = kq8 * 16 + (it + 1) * 2;
            nA0 = *(const uint4*)&srcA[(size_t)kcn * 2048 + tA];
            nA1 = *(const uint4*)&srcA[(size_t)(kcn + 1) * 2048 + tA];
            nB0 = *(const uint4*)&srcB[(bRow + kcn) * 512 + eB];
            nB1 = *(const uint4*)&srcB[(bRow + kcn + 1) * 512 + eB];
        }

        // Compute current chunk: 2 kc x 6 MFMA (order identical to v7).
#pragma unroll
        for (int j = 0; j < 2; ++j) {
            const int jo = j * 4096;
            bf16x8 bh = *(const bf16x8*)&lds[8192 + jo + nq * 512 + lane * 8];
            bf16x8 bl = *(const bf16x8*)&lds[10240 + jo + nq * 512 + lane * 8];
#pragma unroll
            for (int f = 0; f < 2; ++f) {
                const int mq = mh * 2 + f;
                bf16x8 ah = *(const bf16x8*)&lds[jo + mq * 512 + lane * 8];
                bf16x8 al = *(const bf16x8*)&lds[jo + 2048 + mq * 512 + lane * 8];
                acc[f] = __builtin_amdgcn_mfma_f32_16x16x32_bf16(ah, bh, acc[f], 0, 0, 0);
                acc[f] = __builtin_amdgcn_mfma_f32_16x16x32_bf16(al, bh, acc[f], 0, 0, 0);
                acc[f] = __builtin_amdgcn_mfma_f32_16x16x32_bf16(ah, bl, acc[f], 0, 0, 0);
            }
        }

        __syncthreads();                      // all waves done reading buffer
        if (it < 7) {
            *(uint4*)&lds[tid * 8]         = nA0;
            *(uint4*)&lds[4096 + tid * 8]  = nA1;
            *(uint4*)&lds[8192 + tid * 8]  = nB0;
            *(uint4*)&lds[12288 + tid * 8] = nB1;
        }
        __syncthreads();                      // buffer ready for next chunk
    }

    // Direct P store: wave's acc is the complete K-eighth partial.
    // C-frag layout: value(row16=q*4+rg, col=l16) at lane q*16+l16, reg rg.
    {
        const int q = lane >> 4, l16 = lane & 15;
        float* Pb = &P[(size_t)(kq8 * 64 + s64) * 4096];
#pragma unroll
        for (int f = 0; f < 2; ++f) {
            const int mq = mh * 2 + f;
#pragma unroll
            for (int rg = 0; rg < 4; ++rg) {
                const int m = mq * 16 + q * 4 + rg;
                Pb[(size_t)m * 64 + nq * 16 + l16] = acc[f][rg];
            }
        }
    }
}

// ---------------------------------------------------------------------------
// Epilogue kernel: grid 256 x 256 thr; block b -> strip s64 = b>>2,
// row-quarter mq4 = b&3. Thread t: row, 4 cols. Sums 8 K-eighth partials,
// applies b/alpha/clip/sigmoid, updates x, writes next-step A-fragments.
// Cross-kernel P visibility via the dispatch boundary (baseline-proven).
// ---------------------------------------------------------------------------
__global__ __launch_bounds__(256) void epi_kernel(
    const float* __restrict__ P,
    float* __restrict__ x,
    unsigned short* __restrict__ gfh_out,
    unsigned short* __restrict__ gfl_out,
    const float* __restrict__ bvec,
    const float* __restrict__ beta,
    const float* __restrict__ tau,
    const float* __restrict__ dt_ptr,
    const float* __restrict__ maxx_ptr,
    float* __restrict__ gout_f32)             // non-null on last step only
{
    const int tid = threadIdx.x;
    const int s64 = blockIdx.x >> 2;
    const int mq4 = blockIdx.x & 3;
    const int m   = mq4 * 16 + (tid >> 4);    // batch row 0..63
    const int tt  = tid & 15;
    const int c0  = tt * 4;
    const int n0  = s64 * 64 + c0;            // global col, 4-aligned

    const size_t pb = ((size_t)s64 * 64 + m) * 64 + c0;
    float sum[4] = {};
#pragma unroll
    for (int k8 = 0; k8 < 8; ++k8) {
        float4 p = *(const float4*)&P[(size_t)k8 * 262144 + pb];
        sum[0] += p.x; sum[1] += p.y; sum[2] += p.z; sum[3] += p.w;
    }

    const float dt = *dt_ptr;
    const float mx = *maxx_ptr;
    float4 b0 = *(const float4*)&bvec[n0];
    float4 e0 = *(const float4*)&beta[n0];
    float4 t0 = *(const float4*)&tau[n0];
    float bb[4] = {b0.x, b0.y, b0.z, b0.w};
    float be[4] = {e0.x, e0.y, e0.z, e0.w};
    float tv[4] = {t0.x, t0.y, t0.z, t0.w};

    float* xp = &x[(size_t)m * NN + n0];
    float4 x0 = *(const float4*)xp;
    float xo[4] = {x0.x, x0.y, x0.z, x0.w};

    float gg[4];
    unsigned short vh[4], vl[4];
#pragma unroll
    for (int j = 0; j < 4; ++j) {
        const float al = dt / tv[j];
        float xn = al * (sum[j] + bb[j]) + (1.0f - al) * xo[j];
        xn = fminf(fmaxf(xn, -mx), mx);
        float g = 1.0f / (1.0f + __expf(-be[j] * xn));
        xo[j] = xn;
        gg[j] = g;
        unsigned short hi = f2bf(g);
        vh[j] = hi;
        vl[j] = f2bf(g - bf2f(hi));
    }
    *(float4*)xp = {xo[0], xo[1], xo[2], xo[3]};

    // A-fragment scatter for (m, kg = n0..n0+3); n0%8 in {0,4} -> ushort4.
    size_t off = (((size_t)(n0 >> 5) * 4 + (m >> 4)) * 64 + ((n0 & 31) >> 3) * 16 + (m & 15)) * 8 + (n0 & 7);
    *(ushort4*)&gfh_out[off] = {vh[0], vh[1], vh[2], vh[3]};
    *(ushort4*)&gfl_out[off] = {vl[0], vl[1], vl[2], vl[3]};

    if (gout_f32)
        *(float4*)&gout_f32[(size_t)m * NN + n0] = {gg[0], gg[1], gg[2], gg[3]};
}

// ---------------------------------------------------------------------------
extern "C" void kernel_launch(void* const* d_in, const int* in_sizes, int n_in,
                              void* d_out, int out_size, void* d_ws, size_t ws_size,
                              hipStream_t stream) {
    const float* state_g = (const float*)d_in[0];
    const float* W       = (const float*)d_in[1];
    const float* b       = (const float*)d_in[2];
    const float* beta    = (const float*)d_in[3];
    const float* tau     = (const float*)d_in[4];
    const float* dt      = (const float*)d_in[5];
    float* out = (float*)d_out;

    char* ws = (char*)d_ws;
    const size_t WH = (size_t)KK * NN * 2;    // 32 MB per W-frag array
    const size_t XB = (size_t)MM * NN * 4;    // 1 MB
    const size_t GB = (size_t)MM * NN * 2;    // 512 KB per g-frag array
    const size_t PB = (size_t)8 * 64 * 64 * 64 * 4;   // 8 MB partials
    unsigned short* Wfh = (unsigned short*)ws;
    unsigned short* Wfl = (unsigned short*)(ws + WH);
    float*          x   = (float*)(ws + 2 * WH);
    unsigned short* g0h = (unsigned short*)(ws + 2 * WH + XB);
    unsigned short* g0l = (unsigned short*)(ws + 2 * WH + XB + GB);
    unsigned short* g1h = (unsigned short*)(ws + 2 * WH + XB + 2 * GB);
    unsigned short* g1l = (unsigned short*)(ws + 2 * WH + XB + 3 * GB);
    float*          P   = (float*)(ws + 2 * WH + XB + 4 * GB);
    float*          mxp = (float*)(ws + 2 * WH + XB + 4 * GB + PB);

    symm_kernel<<<dim3(64, 64), 256, 0, stream>>>(W, Wfh, Wfl);
    init_kernel<<<(MM * NN) / 256, 256, 0, stream>>>(state_g, beta, x, g0h, g0l);
    maxx_kernel<<<1, 256, 0, stream>>>(beta, mxp);

    unsigned short *gih = g0h, *gil = g0l, *goh = g1h, *gol = g1l;
    for (int st = 0; st < NSTEP; ++st) {
        float* of = (st == NSTEP - 1) ? out : nullptr;
        gemm_kernel<<<512, 512, 0, stream>>>(gih, gil, Wfh, Wfl, P);
        epi_kernel<<<256, 256, 0, stream>>>(P, x, goh, gol, b, beta, tau, dt, mxp, of);
        unsigned short* tp;
        tp = gih; gih = goh; goh = tp;
        tp = gil; gil = gol; gol = tp;
    }
}